// Round 18
// baseline (67.872 us; speedup 1.0000x reference)
//
#include <hip/hip_runtime.h>
#include <math.h>

#define N_NODES 8192
#define KNN 9

// order-preserving float->uint map packed with index: exact (d, idx) lex order
__device__ __forceinline__ unsigned long long packdi(float d, int idx) {
  unsigned int u = __float_as_uint(d);
  u = (u & 0x80000000u) ? ~u : (u | 0x80000000u);
  return ((unsigned long long)u << 32) | (unsigned int)idx;
}

// K1: x[B,C,H,W] -> xf[N,C] via LDS tile transpose (coalesced both ways);
// sq[n] = ||xf[n]||^2 ; zero deg.
__global__ __launch_bounds__(256) void k_prep(const float* __restrict__ x,
                                              float* __restrict__ xf,
                                              float* __restrict__ sq,
                                              int* __restrict__ deg) {
  __shared__ float t[64][65];
  const int b = blockIdx.x >> 4;
  const int hw0 = (blockIdx.x & 15) * 64;
  const int c0 = threadIdx.x >> 6;      // 0..3
  const int hwl = threadIdx.x & 63;
#pragma unroll
  for (int i = 0; i < 16; ++i) {
    int c = i * 4 + c0;
    t[c][hwl] = x[((size_t)(b * 64 + c)) * 1024 + hw0 + hwl];
  }
  __syncthreads();
  const int wave = threadIdx.x >> 6;    // 0..3
  const int lane = threadIdx.x & 63;    // channel
#pragma unroll
  for (int i = 0; i < 16; ++i) {
    int r = i * 4 + wave;               // hw row within tile
    float v = t[lane][r];
    int n = b * 1024 + hw0 + r;
    xf[(size_t)n * 64 + lane] = v;      // lanes along c -> 256B contiguous
    float s = v * v;
#pragma unroll
    for (int m = 1; m < 64; m <<= 1) s += __shfl_xor(s, m);
    if (lane == 0) sq[n] = s;
  }
  int tid = blockIdx.x * 256 + threadIdx.x;
  if (tid < N_NODES) deg[tid] = 0;
}

// K2 (k_dist): staged distance GEMM. R17 was LDS-PIPE-bound (occupancy fix
// was null: LDS BW is per-CU), so this round cuts LDS instructions 25%:
// micro-tile 16q x 8c (6 b128 per 32 FMA-instr vs 4 per 16). Tile =
// 128q x 256c, K=64, 256 threads, grid (64,4). All global reads LDS-staged
// once per block (R12-14: direct streaming => ~490MB L2-miss traffic).
// Qs[64][128] 32KB staged once; Cs[16][256] 16KB staged 4x. C-fragment
// cols split {tc*4, 128+tc*4} -> stride-16B reads, 2-way (free); Q-frag
// reads are 2-address wave broadcasts (free). acc[16][8] statically
// indexed everywhere (rule #20). d2 written coalesced; selection in k_sel.
__global__ __launch_bounds__(256, 2) void k_dist(const float* __restrict__ x,
                                                 const float* __restrict__ sq,
                                                 float* __restrict__ d2g) {
  __shared__ float Qs[64][128];   // 32KB
  __shared__ float Cs[16][256];   // 16KB, staged 4x
  const int t = threadIdx.x;
  const int q0 = blockIdx.x * 128;
  const int b = q0 >> 10;
  const int bstart = b << 10;
  const int cb0 = blockIdx.y * 256;          // col within batch
  const float4* xb4 = reinterpret_cast<const float4*>(x) + (size_t)b * 16384;

  // stage Q tile: Qs[k][ql] = x[b][k][(q0-bstart)+ql]   (coalesced)
  const int qoff4 = (q0 - bstart) >> 2;
#pragma unroll
  for (int i = 0; i < 8; ++i) {
    int idx = i * 256 + t;                   // 0..2047, 32 float4 per k-row
    int k = idx >> 5, c4 = idx & 31;
    float4 v = xb4[(size_t)k * 256 + qoff4 + c4];
    *reinterpret_cast<float4*>(&Qs[k][c4 * 4]) = v;
  }

  const int tq = t >> 5;    // 0..7  -> q rows tq*16..+15
  const int tc = t & 31;    // 0..31 -> c cols {tc*4..+3} U {128+tc*4..+3}

  float acc[16][8];
#pragma unroll
  for (int i = 0; i < 16; ++i)
#pragma unroll
    for (int j = 0; j < 8; ++j) acc[i][j] = 0.f;

  const int cb4 = cb0 >> 2;
#pragma unroll
  for (int kh = 0; kh < 4; ++kh) {
    __syncthreads();                         // Qs ready / prev stage's FMA done
#pragma unroll
    for (int i = 0; i < 4; ++i) {
      int idx = i * 256 + t;                 // 0..1023, 64 float4 per k-row
      int k = idx >> 6, c4 = idx & 63;
      float4 v = xb4[(size_t)(kh * 16 + k) * 256 + cb4 + c4];
      *reinterpret_cast<float4*>(&Cs[k][c4 * 4]) = v;
    }
    __syncthreads();                         // Cs ready
#pragma unroll 2
    for (int k = 0; k < 16; ++k) {
      float4 qa = *reinterpret_cast<const float4*>(&Qs[kh * 16 + k][tq * 16]);
      float4 qb = *reinterpret_cast<const float4*>(&Qs[kh * 16 + k][tq * 16 + 4]);
      float4 qc = *reinterpret_cast<const float4*>(&Qs[kh * 16 + k][tq * 16 + 8]);
      float4 qd = *reinterpret_cast<const float4*>(&Qs[kh * 16 + k][tq * 16 + 12]);
      float4 ca = *reinterpret_cast<const float4*>(&Cs[k][tc * 4]);
      float4 cb = *reinterpret_cast<const float4*>(&Cs[k][128 + tc * 4]);
      float qv[16] = {qa.x, qa.y, qa.z, qa.w, qb.x, qb.y, qb.z, qb.w,
                      qc.x, qc.y, qc.z, qc.w, qd.x, qd.y, qd.z, qd.w};
      float cv[8] = {ca.x, ca.y, ca.z, ca.w, cb.x, cb.y, cb.z, cb.w};
#pragma unroll
      for (int i = 0; i < 16; ++i)
#pragma unroll
        for (int j = 0; j < 8; ++j)
          acc[i][j] = fmaf(qv[i], cv[j], acc[i][j]);
    }
  }

  // epilogue: d2 = (sqq + csq) - 2*dot ; two coalesced float4 per row
  float sqq[16], csq[8];
#pragma unroll
  for (int i = 0; i < 16; ++i) sqq[i] = sq[q0 + tq * 16 + i];
  {
    float4 c1 = *reinterpret_cast<const float4*>(sq + bstart + cb0 + tc * 4);
    float4 c2 = *reinterpret_cast<const float4*>(sq + bstart + cb0 + 128 + tc * 4);
    csq[0] = c1.x; csq[1] = c1.y; csq[2] = c1.z; csq[3] = c1.w;
    csq[4] = c2.x; csq[5] = c2.y; csq[6] = c2.z; csq[7] = c2.w;
  }
#pragma unroll
  for (int i = 0; i < 16; ++i) {
    float* orow = d2g + (size_t)(q0 + tq * 16 + i) * 1024 + cb0;
    float4 o1, o2;
    o1.x = fmaf(-2.f, acc[i][0], sqq[i] + csq[0]);
    o1.y = fmaf(-2.f, acc[i][1], sqq[i] + csq[1]);
    o1.z = fmaf(-2.f, acc[i][2], sqq[i] + csq[2]);
    o1.w = fmaf(-2.f, acc[i][3], sqq[i] + csq[3]);
    o2.x = fmaf(-2.f, acc[i][4], sqq[i] + csq[4]);
    o2.y = fmaf(-2.f, acc[i][5], sqq[i] + csq[5]);
    o2.z = fmaf(-2.f, acc[i][6], sqq[i] + csq[6]);
    o2.w = fmaf(-2.f, acc[i][7], sqq[i] + csq[7]);
    *reinterpret_cast<float4*>(orow + tc * 4) = o1;
    *reinterpret_cast<float4*>(orow + 128 + tc * 4) = o2;
  }
}

// K3 (k_sel): one WAVE per query (coalesced: per load-instr the wave reads
// 1KB contiguous of the query's d2 row). 16 named u64 packs (orderedbits::idx),
// 9 rounds of {strict-min over packs > last} + 64-lane argmin = exact
// (d,idx)-lex top_k incl. ties. (Validated R10/R11/R15/R17.)
__global__ __launch_bounds__(256) void k_sel(const float* __restrict__ d2g,
                                             int* __restrict__ idxf,
                                             int* __restrict__ deg) {
  const int lane = threadIdx.x & 63;
  const int q = blockIdx.x * 4 + (threadIdx.x >> 6);

  if (q == N_NODES - 1) {
    // batch 8 = {8191}: self first, then -inf ties filled with indices 0..7
    if (lane < KNN) {
      int nb = (lane == 0) ? (N_NODES - 1) : (lane - 1);
      idxf[q * KNN + lane] = nb;
      if (nb != q) atomicAdd(&deg[nb], 1);
    }
    return;
  }

  const int bstart = (q >> 10) << 10;
  const int lim = (bstart == 7168) ? 1023 : 1024;   // exclude node 8191
  const float4* row = reinterpret_cast<const float4*>(d2g + (size_t)q * 1024);
  const int c0 = lane * 4;

  float4 v0 = row[lane];
  float4 v1 = row[64 + lane];
  float4 v2 = row[128 + lane];
  float4 v3 = row[192 + lane];

  unsigned long long u0, u1, u2, u3, u4, u5, u6, u7;
  unsigned long long u8, u9, u10, u11, u12, u13, u14, u15;
  u0  = (c0 + 0 < lim) ? packdi(v0.x, bstart + c0 + 0) : ~0ULL;
  u1  = (c0 + 1 < lim) ? packdi(v0.y, bstart + c0 + 1) : ~0ULL;
  u2  = (c0 + 2 < lim) ? packdi(v0.z, bstart + c0 + 2) : ~0ULL;
  u3  = (c0 + 3 < lim) ? packdi(v0.w, bstart + c0 + 3) : ~0ULL;
  u4  = (c0 + 256 < lim) ? packdi(v1.x, bstart + c0 + 256) : ~0ULL;
  u5  = (c0 + 257 < lim) ? packdi(v1.y, bstart + c0 + 257) : ~0ULL;
  u6  = (c0 + 258 < lim) ? packdi(v1.z, bstart + c0 + 258) : ~0ULL;
  u7  = (c0 + 259 < lim) ? packdi(v1.w, bstart + c0 + 259) : ~0ULL;
  u8  = (c0 + 512 < lim) ? packdi(v2.x, bstart + c0 + 512) : ~0ULL;
  u9  = (c0 + 513 < lim) ? packdi(v2.y, bstart + c0 + 513) : ~0ULL;
  u10 = (c0 + 514 < lim) ? packdi(v2.z, bstart + c0 + 514) : ~0ULL;
  u11 = (c0 + 515 < lim) ? packdi(v2.w, bstart + c0 + 515) : ~0ULL;
  u12 = (c0 + 768 < lim) ? packdi(v3.x, bstart + c0 + 768) : ~0ULL;
  u13 = (c0 + 769 < lim) ? packdi(v3.y, bstart + c0 + 769) : ~0ULL;
  u14 = (c0 + 770 < lim) ? packdi(v3.z, bstart + c0 + 770) : ~0ULL;
  u15 = (c0 + 771 < lim) ? packdi(v3.w, bstart + c0 + 771) : ~0ULL;

  unsigned long long last = 0ULL;   // valid packs are > 0 (finite d2)
#pragma unroll
  for (int r = 0; r < KNN; ++r) {
    unsigned long long cand = ~0ULL;
#define CHK(uu) { unsigned long long pk = (uu); \
                  if (pk > last && pk < cand) cand = pk; }
    CHK(u0) CHK(u1) CHK(u2) CHK(u3) CHK(u4) CHK(u5) CHK(u6) CHK(u7)
    CHK(u8) CHK(u9) CHK(u10) CHK(u11) CHK(u12) CHK(u13) CHK(u14) CHK(u15)
#undef CHK
    unsigned long long m = cand;
#pragma unroll
    for (int msk = 1; msk < 64; msk <<= 1) {
      unsigned long long o = __shfl_xor(m, msk);
      if (o < m) m = o;
    }
    if (lane == r) {
      int bi = (int)(unsigned int)(m & 0xffffffffu);
      idxf[q * KNN + r] = bi;
      if (bi != q) atomicAdd(&deg[bi], 1);
    }
    last = m;                       // next round: strictly greater packs
  }
}

// K4 (fused gather + output GEMM), 32 nodes/block, grid 256, 2 rows/thread:
// each weight b128 LDS read now feeds 2 output rows (halves the GEMM-phase
// LDS-pipe instructions, ~5us -> ~2.6us); gather phase has 2 items/thread =
// 18 independent scattered loads of ILP to cover L2 latency at 1 block/CU.
__global__ __launch_bounds__(256) void k_gout(const float* __restrict__ xf,
                                              const int* __restrict__ idxf,
                                              const int* __restrict__ deg,
                                              const float* __restrict__ W0,
                                              const float* __restrict__ W1,
                                              const float* __restrict__ bias,
                                              float* __restrict__ out) {
  __shared__ float w0[64 * 64];
  __shared__ float w1[64 * 64];
  __shared__ float sx[32 * 68];
  __shared__ float sg[32 * 68];
  const int nb = blockIdx.x * 32;
  const int t = threadIdx.x;

  float4* w04 = reinterpret_cast<float4*>(w0);
  float4* w14 = reinterpret_cast<float4*>(w1);
  const float4* W04 = reinterpret_cast<const float4*>(W0);
  const float4* W14 = reinterpret_cast<const float4*>(W1);
#pragma unroll
  for (int i = 0; i < 4; ++i) { w04[i * 256 + t] = W04[i * 256 + t]; w14[i * 256 + t] = W14[i * 256 + t]; }
#pragma unroll
  for (int i = 0; i < 2; ++i) {
    int idx = i * 256 + t;
    int ln = idx >> 4, c4 = idx & 15;
    float4 v = reinterpret_cast<const float4*>(xf + (size_t)(nb + ln) * 64)[c4];
    *reinterpret_cast<float4*>(&sx[ln * 68 + c4 * 4]) = v;
  }
  // gather phase: 2 items/thread, item = (node ln, channel-quad c4)
#pragma unroll
  for (int it = 0; it < 2; ++it) {
    int item = it * 256 + t;
    int ln = item >> 4, c4 = item & 15;
    int n = nb + ln;
    int dt = deg[n];
    float dis_t = dt > 0 ? 1.f / sqrtf((float)dt) : 0.f;
    float ax = 0.f, ay = 0.f, az = 0.f, aw = 0.f;
#pragma unroll
    for (int k = 0; k < 9; ++k) {
      int s = idxf[n * KNN + k];
      if (s == n) continue;                    // self loop: w=0 -> norm 0
      int ds = deg[s];
      float dis_s = ds > 0 ? 1.f / sqrtf((float)ds) : 0.f;
      float w = -dis_s * dis_t;
      float4 v = reinterpret_cast<const float4*>(xf + (size_t)s * 64)[c4];
      ax = fmaf(w, v.x, ax); ay = fmaf(w, v.y, ay);
      az = fmaf(w, v.z, az); aw = fmaf(w, v.w, aw);
    }
    float4 r; r.x = ax; r.y = ay; r.z = az; r.w = aw;
    *reinterpret_cast<float4*>(&sg[ln * 68 + c4 * 4]) = r;
  }
  __syncthreads();

  const int ln2 = t >> 4, o4 = t & 15;        // rows ln2 and ln2+16
  float4 bv = reinterpret_cast<const float4*>(bias)[o4];
  float4 a0 = bv, a1 = bv;
#pragma unroll
  for (int c = 0; c < 64; ++c) {
    float4 v0 = reinterpret_cast<const float4*>(w0 + c * 64)[o4];
    float4 v1 = reinterpret_cast<const float4*>(w1 + c * 64)[o4];
    float xv0 = sx[ln2 * 68 + c],        gv0 = sg[ln2 * 68 + c];
    float xv1 = sx[(ln2 + 16) * 68 + c], gv1 = sg[(ln2 + 16) * 68 + c];
    a0.x = fmaf(xv0, v0.x, a0.x); a0.y = fmaf(xv0, v0.y, a0.y);
    a0.z = fmaf(xv0, v0.z, a0.z); a0.w = fmaf(xv0, v0.w, a0.w);
    a0.x = fmaf(gv0, v1.x, a0.x); a0.y = fmaf(gv0, v1.y, a0.y);
    a0.z = fmaf(gv0, v1.z, a0.z); a0.w = fmaf(gv0, v1.w, a0.w);
    a1.x = fmaf(xv1, v0.x, a1.x); a1.y = fmaf(xv1, v0.y, a1.y);
    a1.z = fmaf(xv1, v0.z, a1.z); a1.w = fmaf(xv1, v0.w, a1.w);
    a1.x = fmaf(gv1, v1.x, a1.x); a1.y = fmaf(gv1, v1.y, a1.y);
    a1.z = fmaf(gv1, v1.z, a1.z); a1.w = fmaf(gv1, v1.w, a1.w);
  }
  reinterpret_cast<float4*>(out)[(size_t)(nb + ln2) * 16 + o4] = a0;
  reinterpret_cast<float4*>(out)[(size_t)(nb + ln2 + 16) * 16 + o4] = a1;
}

extern "C" void kernel_launch(void* const* d_in, const int* in_sizes, int n_in,
                              void* d_out, int out_size, void* d_ws, size_t ws_size,
                              hipStream_t stream) {
  const float* x    = (const float*)d_in[0];
  const float* W0   = (const float*)d_in[1];
  const float* W1   = (const float*)d_in[2];
  const float* bias = (const float*)d_in[3];
  float* out = (float*)d_out;
  char* ws = (char*)d_ws;

  // workspace layout: xf 2MB, sq 32KB, deg 32KB, idxf 288KB, d2g 33.5MB
  float* xf   = (float*)(ws);
  float* sq   = (float*)(ws + 2097152);
  int*   deg  = (int*)  (ws + 2129920);
  int*   idxf = (int*)  (ws + 2162688);
  float* d2g  = (float*)(ws + 2457600);

  k_prep<<<128, 256, 0, stream>>>(x, xf, sq, deg);
  k_dist<<<dim3(64, 4), 256, 0, stream>>>(x, sq, d2g);
  k_sel <<<2048, 256, 0, stream>>>(d2g, idxf, deg);
  k_gout<<<256, 256, 0, stream>>>(xf, idxf, deg, W0, W1, bias, out);
}

// Round 19
// 53.153 us; speedup vs baseline: 1.2769x; 1.2769x over previous
//
#include <hip/hip_runtime.h>
#include <math.h>

#define N_NODES 8192
#define KNN 9

// order-preserving float->uint map packed with index: exact (d, idx) lex order
__device__ __forceinline__ unsigned long long packdi(float d, int idx) {
  unsigned int u = __float_as_uint(d);
  u = (u & 0x80000000u) ? ~u : (u | 0x80000000u);
  return ((unsigned long long)u << 32) | (unsigned int)idx;
}

// K1 (k_dist, with k_prep fused away): staged distance GEMM (R15 structure,
// session-best). Block = 128q x 128c, K=64, 256 threads, micro 8q x 8c.
// All global reads LDS-staged once per block (R12-14: direct streaming =>
// ~490MB L2-miss traffic; staged => 8.6MB). NEW vs R15: the norms sq are
// computed IN-BLOCK from the staged tiles (sequential-k fmaf for both query
// and candidate norms -> bit-identical values per node), xf is written by
// transposing Qs (each (x,y) block writes channel-quads {2y, 2y+1} for its
// 128 queries; 2-way-bank column reads = free), and deg is zeroed here
// (16 entries per block; consumed only by the later k_sel). This deletes
// the separate k_prep kernel + one launch from the critical path.
__global__ __launch_bounds__(256, 2) void k_dist(const float* __restrict__ x,
                                                 float* __restrict__ xf,
                                                 int* __restrict__ deg,
                                                 float* __restrict__ d2g) {
  __shared__ float Qs[64][128];   // 32KB
  __shared__ float Cs[32][128];   // 16KB, staged 2x
  __shared__ float sql[128];      // query norms
  __shared__ float csql[128];     // candidate norms
  const int t = threadIdx.x;
  const int q0 = blockIdx.x * 128;
  const int b = q0 >> 10;
  const int bstart = b << 10;
  const int by = blockIdx.y;
  const int cb0 = by * 128;                  // col within batch
  const float4* xb4 = reinterpret_cast<const float4*>(x) + (size_t)b * 16384;

  // stage Q tile: Qs[k][ql] = x[b][k][(q0-bstart)+ql]   (coalesced)
  const int qoff4 = (q0 - bstart) >> 2;
#pragma unroll
  for (int i = 0; i < 8; ++i) {
    int idx = i * 256 + t;                   // 0..2047, 32 float4 per k-row
    int k = idx >> 5, c4 = idx & 31;
    float4 v = xb4[(size_t)k * 256 + qoff4 + c4];
    *reinterpret_cast<float4*>(&Qs[k][c4 * 4]) = v;
  }
  __syncthreads();                           // Qs ready

  // query norms (sequential k, fmaf): sql[q] = ||x_q||^2
  if (t < 128) {
    float s = 0.f;
#pragma unroll
    for (int k = 0; k < 64; ++k) { float v = Qs[k][t]; s = fmaf(v, v, s); }
    sql[t] = s;
  }
  // xf write: this block covers channel-quads {2*by, 2*by+1} of its queries
  {
    int ql = t >> 1, c4 = by * 2 + (t & 1);
    float4 v;
    v.x = Qs[c4 * 4 + 0][ql];
    v.y = Qs[c4 * 4 + 1][ql];
    v.z = Qs[c4 * 4 + 2][ql];
    v.w = Qs[c4 * 4 + 3][ql];
    reinterpret_cast<float4*>(xf)[(size_t)(q0 + ql) * 16 + c4] = v;
  }
  // deg zero: 16 entries per block (q0 + by*16 ..); k_sel consumes later
  if (t < 16) deg[q0 + by * 16 + t] = 0;

  const int tq = t >> 4;    // 0..15 -> q rows tq*8..+7
  const int tc = t & 15;    // 0..15 -> c cols {tc*4..+3} U {64+tc*4..+3}

  float acc[8][8];
#pragma unroll
  for (int i = 0; i < 8; ++i)
#pragma unroll
    for (int j = 0; j < 8; ++j) acc[i][j] = 0.f;

  float csqr = 0.f;                          // candidate-norm partial (t<128)
  const int cb4 = cb0 >> 2;
#pragma unroll
  for (int kh = 0; kh < 2; ++kh) {
    __syncthreads();                         // Qs/xf reads & prev FMA done
#pragma unroll
    for (int i = 0; i < 4; ++i) {
      int idx = i * 256 + t;                 // 0..1023, 32 float4 per k-row
      int k = idx >> 5, c4 = idx & 31;
      float4 v = xb4[(size_t)(kh * 32 + k) * 256 + cb4 + c4];
      *reinterpret_cast<float4*>(&Cs[k][c4 * 4]) = v;
    }
    __syncthreads();                         // Cs ready
    if (t < 128) {                           // candidate norms, sequential k
      float s = csqr;
#pragma unroll
      for (int k = 0; k < 32; ++k) { float v = Cs[k][t]; s = fmaf(v, v, s); }
      csqr = s;
    }
#pragma unroll 2
    for (int k = 0; k < 32; ++k) {
      float4 qa = *reinterpret_cast<const float4*>(&Qs[kh * 32 + k][tq * 8]);
      float4 qb = *reinterpret_cast<const float4*>(&Qs[kh * 32 + k][tq * 8 + 4]);
      float4 ca = *reinterpret_cast<const float4*>(&Cs[k][tc * 4]);
      float4 cb = *reinterpret_cast<const float4*>(&Cs[k][64 + tc * 4]);
      float qv[8] = {qa.x, qa.y, qa.z, qa.w, qb.x, qb.y, qb.z, qb.w};
      float cv[8] = {ca.x, ca.y, ca.z, ca.w, cb.x, cb.y, cb.z, cb.w};
#pragma unroll
      for (int i = 0; i < 8; ++i)
#pragma unroll
        for (int j = 0; j < 8; ++j)
          acc[i][j] = fmaf(qv[i], cv[j], acc[i][j]);
    }
  }
  if (t < 128) csql[t] = csqr;
  __syncthreads();                           // norms ready

  // epilogue: d2 = (sqq + csq) - 2*dot ; two coalesced float4 per row
  float sqq[8], csq[8];
#pragma unroll
  for (int i = 0; i < 8; ++i) sqq[i] = sql[tq * 8 + i];
#pragma unroll
  for (int j = 0; j < 4; ++j) { csq[j] = csql[tc * 4 + j]; csq[4 + j] = csql[64 + tc * 4 + j]; }
#pragma unroll
  for (int i = 0; i < 8; ++i) {
    float* orow = d2g + (size_t)(q0 + tq * 8 + i) * 1024 + cb0;
    float4 o1, o2;
    o1.x = fmaf(-2.f, acc[i][0], sqq[i] + csq[0]);
    o1.y = fmaf(-2.f, acc[i][1], sqq[i] + csq[1]);
    o1.z = fmaf(-2.f, acc[i][2], sqq[i] + csq[2]);
    o1.w = fmaf(-2.f, acc[i][3], sqq[i] + csq[3]);
    o2.x = fmaf(-2.f, acc[i][4], sqq[i] + csq[4]);
    o2.y = fmaf(-2.f, acc[i][5], sqq[i] + csq[5]);
    o2.z = fmaf(-2.f, acc[i][6], sqq[i] + csq[6]);
    o2.w = fmaf(-2.f, acc[i][7], sqq[i] + csq[7]);
    *reinterpret_cast<float4*>(orow + tc * 4) = o1;
    *reinterpret_cast<float4*>(orow + 64 + tc * 4) = o2;
  }
}

// K2 (k_sel): one WAVE per query (coalesced: per load-instr the wave reads
// 1KB contiguous of the query's d2 row). 16 named u64 packs (orderedbits::idx),
// 9 rounds of {strict-min over packs > last} + 64-lane argmin = exact
// (d,idx)-lex top_k incl. ties. (Validated R10/R11/R15/R17.)
__global__ __launch_bounds__(256) void k_sel(const float* __restrict__ d2g,
                                             int* __restrict__ idxf,
                                             int* __restrict__ deg) {
  const int lane = threadIdx.x & 63;
  const int q = blockIdx.x * 4 + (threadIdx.x >> 6);

  if (q == N_NODES - 1) {
    // batch 8 = {8191}: self first, then -inf ties filled with indices 0..7
    if (lane < KNN) {
      int nb = (lane == 0) ? (N_NODES - 1) : (lane - 1);
      idxf[q * KNN + lane] = nb;
      if (nb != q) atomicAdd(&deg[nb], 1);
    }
    return;
  }

  const int bstart = (q >> 10) << 10;
  const int lim = (bstart == 7168) ? 1023 : 1024;   // exclude node 8191
  const float4* row = reinterpret_cast<const float4*>(d2g + (size_t)q * 1024);
  const int c0 = lane * 4;

  float4 v0 = row[lane];
  float4 v1 = row[64 + lane];
  float4 v2 = row[128 + lane];
  float4 v3 = row[192 + lane];

  unsigned long long u0, u1, u2, u3, u4, u5, u6, u7;
  unsigned long long u8, u9, u10, u11, u12, u13, u14, u15;
  u0  = (c0 + 0 < lim) ? packdi(v0.x, bstart + c0 + 0) : ~0ULL;
  u1  = (c0 + 1 < lim) ? packdi(v0.y, bstart + c0 + 1) : ~0ULL;
  u2  = (c0 + 2 < lim) ? packdi(v0.z, bstart + c0 + 2) : ~0ULL;
  u3  = (c0 + 3 < lim) ? packdi(v0.w, bstart + c0 + 3) : ~0ULL;
  u4  = (c0 + 256 < lim) ? packdi(v1.x, bstart + c0 + 256) : ~0ULL;
  u5  = (c0 + 257 < lim) ? packdi(v1.y, bstart + c0 + 257) : ~0ULL;
  u6  = (c0 + 258 < lim) ? packdi(v1.z, bstart + c0 + 258) : ~0ULL;
  u7  = (c0 + 259 < lim) ? packdi(v1.w, bstart + c0 + 259) : ~0ULL;
  u8  = (c0 + 512 < lim) ? packdi(v2.x, bstart + c0 + 512) : ~0ULL;
  u9  = (c0 + 513 < lim) ? packdi(v2.y, bstart + c0 + 513) : ~0ULL;
  u10 = (c0 + 514 < lim) ? packdi(v2.z, bstart + c0 + 514) : ~0ULL;
  u11 = (c0 + 515 < lim) ? packdi(v2.w, bstart + c0 + 515) : ~0ULL;
  u12 = (c0 + 768 < lim) ? packdi(v3.x, bstart + c0 + 768) : ~0ULL;
  u13 = (c0 + 769 < lim) ? packdi(v3.y, bstart + c0 + 769) : ~0ULL;
  u14 = (c0 + 770 < lim) ? packdi(v3.z, bstart + c0 + 770) : ~0ULL;
  u15 = (c0 + 771 < lim) ? packdi(v3.w, bstart + c0 + 771) : ~0ULL;

  unsigned long long last = 0ULL;   // valid packs are > 0 (finite d2)
#pragma unroll
  for (int r = 0; r < KNN; ++r) {
    unsigned long long cand = ~0ULL;
#define CHK(uu) { unsigned long long pk = (uu); \
                  if (pk > last && pk < cand) cand = pk; }
    CHK(u0) CHK(u1) CHK(u2) CHK(u3) CHK(u4) CHK(u5) CHK(u6) CHK(u7)
    CHK(u8) CHK(u9) CHK(u10) CHK(u11) CHK(u12) CHK(u13) CHK(u14) CHK(u15)
#undef CHK
    unsigned long long m = cand;
#pragma unroll
    for (int msk = 1; msk < 64; msk <<= 1) {
      unsigned long long o = __shfl_xor(m, msk);
      if (o < m) m = o;
    }
    if (lane == r) {
      int bi = (int)(unsigned int)(m & 0xffffffffu);
      idxf[q * KNN + r] = bi;
      if (bi != q) atomicAdd(&deg[bi], 1);
    }
    last = m;                       // next round: strictly greater packs
  }
}

// K3 (fused gather + output GEMM), 16 nodes/block, grid 512 -> 2 blocks/CU
// (R15 form; R18's 32-node/grid-256 variant regressed).
__global__ __launch_bounds__(256) void k_gout(const float* __restrict__ xf,
                                              const int* __restrict__ idxf,
                                              const int* __restrict__ deg,
                                              const float* __restrict__ W0,
                                              const float* __restrict__ W1,
                                              const float* __restrict__ bias,
                                              float* __restrict__ out) {
  __shared__ float w0[64 * 64];
  __shared__ float w1[64 * 64];
  __shared__ float sx[16 * 68];
  __shared__ float sg[16 * 68];
  const int nb = blockIdx.x * 16;
  const int t = threadIdx.x;

  float4* w04 = reinterpret_cast<float4*>(w0);
  float4* w14 = reinterpret_cast<float4*>(w1);
  const float4* W04 = reinterpret_cast<const float4*>(W0);
  const float4* W14 = reinterpret_cast<const float4*>(W1);
#pragma unroll
  for (int i = 0; i < 4; ++i) { w04[i * 256 + t] = W04[i * 256 + t]; w14[i * 256 + t] = W14[i * 256 + t]; }
  {
    int ln = t >> 4, c4 = t & 15;
    float4 v = reinterpret_cast<const float4*>(xf + (size_t)(nb + ln) * 64)[c4];
    *reinterpret_cast<float4*>(&sx[ln * 68 + c4 * 4]) = v;
  }
  // gather phase: 1 item/thread, item = (node ln, channel-quad c4)
  {
    int ln = t >> 4, c4 = t & 15;
    int n = nb + ln;
    int dt = deg[n];
    float dis_t = dt > 0 ? 1.f / sqrtf((float)dt) : 0.f;
    float ax = 0.f, ay = 0.f, az = 0.f, aw = 0.f;
#pragma unroll
    for (int k = 0; k < 9; ++k) {
      int s = idxf[n * KNN + k];
      if (s == n) continue;                    // self loop: w=0 -> norm 0
      int ds = deg[s];
      float dis_s = ds > 0 ? 1.f / sqrtf((float)ds) : 0.f;
      float w = -dis_s * dis_t;
      float4 v = reinterpret_cast<const float4*>(xf + (size_t)s * 64)[c4];
      ax = fmaf(w, v.x, ax); ay = fmaf(w, v.y, ay);
      az = fmaf(w, v.z, az); aw = fmaf(w, v.w, aw);
    }
    float4 r; r.x = ax; r.y = ay; r.z = az; r.w = aw;
    *reinterpret_cast<float4*>(&sg[ln * 68 + c4 * 4]) = r;
  }
  __syncthreads();

  const int ln2 = t >> 4, o4 = t & 15;
  float4 a0 = reinterpret_cast<const float4*>(bias)[o4];
#pragma unroll
  for (int c = 0; c < 64; ++c) {
    float4 v0 = reinterpret_cast<const float4*>(w0 + c * 64)[o4];
    float4 v1 = reinterpret_cast<const float4*>(w1 + c * 64)[o4];
    float xv = sx[ln2 * 68 + c];
    float gv = sg[ln2 * 68 + c];
    a0.x = fmaf(xv, v0.x, a0.x); a0.y = fmaf(xv, v0.y, a0.y);
    a0.z = fmaf(xv, v0.z, a0.z); a0.w = fmaf(xv, v0.w, a0.w);
    a0.x = fmaf(gv, v1.x, a0.x); a0.y = fmaf(gv, v1.y, a0.y);
    a0.z = fmaf(gv, v1.z, a0.z); a0.w = fmaf(gv, v1.w, a0.w);
  }
  reinterpret_cast<float4*>(out)[(size_t)(nb + ln2) * 16 + o4] = a0;
}

extern "C" void kernel_launch(void* const* d_in, const int* in_sizes, int n_in,
                              void* d_out, int out_size, void* d_ws, size_t ws_size,
                              hipStream_t stream) {
  const float* x    = (const float*)d_in[0];
  const float* W0   = (const float*)d_in[1];
  const float* W1   = (const float*)d_in[2];
  const float* bias = (const float*)d_in[3];
  float* out = (float*)d_out;
  char* ws = (char*)d_ws;

  // workspace layout: xf 2MB, deg 32KB, idxf 288KB, d2g 33.5MB
  float* xf   = (float*)(ws);
  int*   deg  = (int*)  (ws + 2097152);
  int*   idxf = (int*)  (ws + 2129920);
  float* d2g  = (float*)(ws + 2424832);

  k_dist<<<dim3(64, 8), 256, 0, stream>>>(x, xf, deg, d2g);
  k_sel <<<2048, 256, 0, stream>>>(d2g, idxf, deg);
  k_gout<<<512, 256, 0, stream>>>(xf, idxf, deg, W0, W1, bias, out);
}